// Round 2
// baseline (1287.890 us; speedup 1.0000x reference)
//
#include <hip/hip_runtime.h>
#include <math.h>

// Problem constants (fixed by setup_inputs)
#define B_ 4
#define C_ 64
#define N_ 16384
#define K_ 16
#define CP 67            // C + 3 (xyz concat)
#define CPAD 68          // padded to 17 float4
#define NP 16            // points per block
#define ESTRIDE 548      // 548 = 4 (mod 32): point rows spread across banks
#define QOFF 1088        // q overlay offset (floats) inside smem (after x area)
#define QSTRIDE 65

// Padded / pre-scaled weights (rewritten every launch by setup_weights)
__device__ __align__(16) float wpad[3 * C_ * CPAD];

__global__ void setup_weights(const float* __restrict__ Wq,
                              const float* __restrict__ Wk,
                              const float* __restrict__ Wv) {
  int i = blockIdx.x * blockDim.x + threadIdx.x;
  if (i >= C_ * CPAD) return;
  int o = i / CPAD, j = i - o * CPAD;
  float q = 0.f, kk = 0.f, v = 0.f;
  if (j < CP) {
    q = Wq[o * CP + j] * 0.35355339059327373f;  // fold 1/sqrt(D), D=8
    kk = Wk[o * CP + j];
    v = Wv[o * CP + j];
  }
  wpad[i] = q;
  wpad[C_ * CPAD + i] = kk;
  wpad[2 * C_ * CPAD + i] = v;
}

// LDS-pipe xor swizzle (32-lane groups). BitMode offset = (xor<<10)|0x1F.
#define SWZ(v, imm) __int_as_float(__builtin_amdgcn_ds_swizzle(__float_as_int(v), (imm)))
#define XOR4S 0x101F
#define XOR8S 0x201F

// VALU-pipe DPP quad permutes (within groups of 4 lanes = one point's k-quad)
#define DPPF(v, ctrl) \
  __int_as_float(__builtin_amdgcn_mov_dpp(__float_as_int(v), (ctrl), 0xF, 0xF, 0))
#define QP_XOR1 0xB1  // [1,0,3,2]
#define QP_XOR2 0x4E  // [2,3,0,1]

template <int CTRL>
__device__ __forceinline__ float qbc(float v) {
  return __int_as_float(__builtin_amdgcn_mov_dpp(__float_as_int(v), CTRL, 0xF, 0xF, 0));
}

// MAC heads 2M (from a) and 2M+1 (from b), broadcast from quad-lane M.
template <int M>
__device__ __forceinline__ void mac2(float& enE, float& enO, float4 a, float4 b,
                                     float x0, float x1, float x2, float x3) {
  enE += qbc<M * 0x55>(a.x) * x0 + qbc<M * 0x55>(a.y) * x1 +
         qbc<M * 0x55>(a.z) * x2 + qbc<M * 0x55>(a.w) * x3;
  enO += qbc<M * 0x55>(b.x) * x0 + qbc<M * 0x55>(b.y) * x1 +
         qbc<M * 0x55>(b.z) * x2 + qbc<M * 0x55>(b.w) * x3;
}

__launch_bounds__(256, 4)
__global__ void pt_attn(const float* __restrict__ pcd,
                        const float* __restrict__ neighbors,
                        const float* __restrict__ xyz,
                        const int* __restrict__ idx_all,
                        float* __restrict__ out) {
  // Single buffer: e-table [16 x 548]; x (1088 fl) and q (1040 fl) overlay its
  // start and are dead before e is written (extra barrier enforces it).
  __shared__ __align__(16) float smem[NP * ESTRIDE];  // 35072 B -> 4 blocks/CU

  const int tid = threadIdx.x;
  const int p = tid >> 4;   // point within tile
  const int k = tid & 15;   // neighbor index
  const int blk = blockIdx.x;
  const int b = blk >> 10;
  const int n0 = (blk & 1023) << 4;
  const int n = n0 + p;

  // ---- neighbor features (B,C,N,K) -> registers; coalesced (256 contiguous
  //      floats per channel across the block) ----
  float nb[CPAD];
  {
    const float* gp = neighbors + (size_t)b * (C_ * N_ * K_) + n0 * K_ + tid;
#pragma unroll
    for (int c = 0; c < C_; ++c)
      nb[c] = gp[(size_t)c * (N_ * K_)];
  }
  {
    const int idx = idx_all[(b * N_ + n) * K_ + k];
    const float* gx = xyz + (size_t)b * (3 * N_) + idx;
    nb[64] = gx[0];
    nb[65] = gx[N_];
    nb[66] = gx[2 * N_];
    nb[67] = 0.f;  // pad (weight pad col is 0 too)
  }

  // ---- stage x = concat(pcd, xyz) for the 16 points (overlay at smem[0]) ----
  {
    const int pp = tid & 15;
    const int c0 = tid >> 4;
#pragma unroll
    for (int it = 0; it < 4; ++it) {
      int c = c0 + it * 16;
      smem[pp * CPAD + c] = pcd[((size_t)b * C_ + c) * N_ + n0 + pp];
    }
    if (tid < 48)
      smem[pp * CPAD + 64 + c0] = xyz[((size_t)b * 3 + c0) * N_ + n0 + pp];
    if (tid < 16)
      smem[pp * CPAD + 67] = 0.f;
  }
  __syncthreads();

  // ---- phase 1: q[o], o = 4k..4k+3 of point p (Wq pre-scaled) ----
  {
    const float4* xr = (const float4*)(smem + p * CPAD);  // broadcast reads
    const float4* wq = (const float4*)(wpad) + 4 * k * 17;
    float a0 = 0.f, a1 = 0.f, a2 = 0.f, a3 = 0.f;
#pragma unroll
    for (int j4 = 0; j4 < 17; ++j4) {
      float4 xv = xr[j4];
      float4 w0 = wq[j4];
      float4 w1 = wq[17 + j4];
      float4 w2 = wq[34 + j4];
      float4 w3 = wq[51 + j4];
      a0 += w0.x * xv.x + w0.y * xv.y + w0.z * xv.z + w0.w * xv.w;
      a1 += w1.x * xv.x + w1.y * xv.y + w1.z * xv.z + w1.w * xv.w;
      a2 += w2.x * xv.x + w2.y * xv.y + w2.z * xv.z + w2.w * xv.w;
      a3 += w3.x * xv.x + w3.y * xv.y + w3.z * xv.z + w3.w * xv.w;
    }
    smem[QOFF + p * QSTRIDE + 4 * k + 0] = a0;
    smem[QOFF + p * QSTRIDE + 4 * k + 1] = a1;
    smem[QOFF + p * QSTRIDE + 4 * k + 2] = a2;
    smem[QOFF + p * QSTRIDE + 4 * k + 3] = a3;
  }
  __syncthreads();

  // ---- phase 2: load q_h, then (after barrier) write e over the overlay ----
  const int h_ = k & 7;
  float qa[8];
#pragma unroll
  for (int d = 0; d < 8; ++d)
    qa[d] = smem[QOFF + p * QSTRIDE + h_ * 8 + d];
  __syncthreads();  // all q reads done before e overwrites x/q overlay

  {
    const int jh = k >> 3;
    const float4* wk = (const float4*)(wpad + C_ * CPAD) + h_ * 8 * 17;
    float4* er = (float4*)(smem + p * ESTRIDE + h_ * CPAD);
#pragma unroll
    for (int u = 0; u < 9; ++u) {
      int j4 = jh * 8 + u;  // j4=8 written by both halves with identical value
      float4 a = make_float4(0.f, 0.f, 0.f, 0.f);
#pragma unroll
      for (int d = 0; d < 8; ++d) {
        float4 w = wk[d * 17 + j4];
        a.x += qa[d] * w.x;
        a.y += qa[d] * w.y;
        a.z += qa[d] * w.z;
        a.w += qa[d] * w.w;
      }
      er[j4] = a;
    }
  }
  __syncthreads();

  // ---- phase 3: en[h] = e[h]·nb_k. Quad-lane c reads only heads {2c,2c+1}
  //      (2 b128/j4), DPP quad-broadcast shares all 8 heads (VALU pipe). ----
  float en[8];
#pragma unroll
  for (int h = 0; h < 8; ++h) en[h] = 0.f;
  {
    const float* e0 = smem + p * ESTRIDE + (2 * (k & 3)) * CPAD;
#pragma unroll
    for (int j4 = 0; j4 < 17; ++j4) {
      float4 a = *(const float4*)(e0 + 4 * j4);          // own even head
      float4 bq = *(const float4*)(e0 + CPAD + 4 * j4);  // own odd head
      float x0 = nb[4 * j4 + 0], x1 = nb[4 * j4 + 1];
      float x2 = nb[4 * j4 + 2], x3 = nb[4 * j4 + 3];
      mac2<0>(en[0], en[1], a, bq, x0, x1, x2, x3);
      mac2<1>(en[2], en[3], a, bq, x0, x1, x2, x3);
      mac2<2>(en[4], en[5], a, bq, x0, x1, x2, x3);
      mac2<3>(en[6], en[7], a, bq, x0, x1, x2, x3);
    }
  }

  // ---- softmax over the 16 k-lanes (xor1/xor2 on DPP, xor4/xor8 on DS) ----
  float at[8];
#pragma unroll
  for (int h = 0; h < 8; ++h) {
    float m = en[h];
    m = fmaxf(m, DPPF(m, QP_XOR1));
    m = fmaxf(m, DPPF(m, QP_XOR2));
    m = fmaxf(m, SWZ(m, XOR4S));
    m = fmaxf(m, SWZ(m, XOR8S));
    float e = __expf(en[h] - m);
    float s = e;
    s += DPPF(s, QP_XOR1);
    s += DPPF(s, QP_XOR2);
    s += SWZ(s, XOR4S);
    s += SWZ(s, XOR8S);
    at[h] = e * __builtin_amdgcn_rcpf(s);
  }

  // ---- pre-permute: ap[i] = at[i ^ g(k)], g(k)=bitrev3(k&7); makes every
  //      reduce level use uniform register indices ----
  float ap[8];
  {
    const bool c4 = (k & 1) != 0;  // g bit2
    const bool c2 = (k & 2) != 0;  // g bit1
    const bool c1 = (k & 4) != 0;  // g bit0
    float t0[8], t1[8];
#pragma unroll
    for (int i = 0; i < 8; ++i) t0[i] = c4 ? at[i ^ 4] : at[i];
#pragma unroll
    for (int i = 0; i < 8; ++i) t1[i] = c2 ? t0[i ^ 2] : t0[i];
#pragma unroll
    for (int i = 0; i < 8; ++i) ap[i] = c1 ? t1[i ^ 1] : t1[i];
  }

  // ---- phase 4: agg_h[j] = sum_k attn[h,k]*nb_k[j]; levels xor1,xor2 on DPP
  //      (4+2 adds), xor4,xor8 on DS (1+1). Lane k ends with head g(k). ----
  const int gk = ((k & 1) << 2) | (k & 2) | ((k & 4) >> 2);
  const int o_base = (gk << 3) | ((k >> 3) << 2);  // 4 output rows per lane
  float xo0 = 0.f, xo1 = 0.f, xo2 = 0.f, xo3 = 0.f;
  const float4* wv = (const float4*)(wpad + 2 * C_ * CPAD) + o_base * 17;
#pragma unroll
  for (int j4 = 0; j4 < 17; ++j4) {
    float agg0, agg1, agg2, agg3;
#pragma unroll
    for (int u = 0; u < 4; ++u) {
      float nbj = nb[4 * j4 + u];
      float s0 = ap[0] * nbj, s1 = ap[1] * nbj, s2 = ap[2] * nbj, s3 = ap[3] * nbj;
      float s4 = ap[4] * nbj, s5 = ap[5] * nbj, s6 = ap[6] * nbj, s7 = ap[7] * nbj;
      s0 += DPPF(s4, QP_XOR1);
      s1 += DPPF(s5, QP_XOR1);
      s2 += DPPF(s6, QP_XOR1);
      s3 += DPPF(s7, QP_XOR1);
      s0 += DPPF(s2, QP_XOR2);
      s1 += DPPF(s3, QP_XOR2);
      s0 += SWZ(s1, XOR4S);
      s0 += SWZ(s0, XOR8S);
      if (u == 0) agg0 = s0;
      else if (u == 1) agg1 = s0;
      else if (u == 2) agg2 = s0;
      else agg3 = s0;
    }
    float4 w0 = wv[j4];
    float4 w1 = wv[17 + j4];
    float4 w2 = wv[34 + j4];
    float4 w3 = wv[51 + j4];
    xo0 += w0.x * agg0 + w0.y * agg1 + w0.z * agg2 + w0.w * agg3;
    xo1 += w1.x * agg0 + w1.y * agg1 + w1.z * agg2 + w1.w * agg3;
    xo2 += w2.x * agg0 + w2.y * agg1 + w2.z * agg2 + w2.w * agg3;
    xo3 += w3.x * agg0 + w3.y * agg1 + w3.z * agg2 + w3.w * agg3;
  }

  // out[b][o][n], o = o_base + i
  float* op = out + ((size_t)b * C_ + o_base) * N_ + n0 + p;
  op[0] = xo0;
  op[(size_t)N_] = xo1;
  op[2 * (size_t)N_] = xo2;
  op[3 * (size_t)N_] = xo3;
}

extern "C" void kernel_launch(void* const* d_in, const int* in_sizes, int n_in,
                              void* d_out, int out_size, void* d_ws, size_t ws_size,
                              hipStream_t stream) {
  const float* pcd = (const float*)d_in[0];
  const float* neighbors = (const float*)d_in[1];
  const float* xyz = (const float*)d_in[2];
  const float* Wq = (const float*)d_in[3];
  const float* Wk = (const float*)d_in[4];
  const float* Wv = (const float*)d_in[5];
  const int* idx = (const int*)d_in[6];
  float* out = (float*)d_out;

  setup_weights<<<(C_ * CPAD + 255) / 256, 256, 0, stream>>>(Wq, Wk, Wv);
  pt_attn<<<B_ * (N_ / NP), 256, 0, stream>>>(pcd, neighbors, xyz, idx, out);
}

// Round 3
// 1015.864 us; speedup vs baseline: 1.2678x; 1.2678x over previous
//
#include <hip/hip_runtime.h>
#include <math.h>

// Problem constants (fixed by setup_inputs)
#define B_ 4
#define C_ 64
#define N_ 16384
#define K_ 16
#define CP 67            // C + 3 (xyz concat)
#define CPAD 68          // padded to 17 float4
#define NP 16            // points per block
#define ESTRIDE 548      // 548 = 4 (mod 32): point rows spread across banks
#define QOFF 1088        // q overlay offset (floats) inside smem (after x area)
#define QSTRIDE 65

// Padded / pre-scaled weights (rewritten every launch by setup_weights)
__device__ __align__(16) float wpad[3 * C_ * CPAD];

__global__ void setup_weights(const float* __restrict__ Wq,
                              const float* __restrict__ Wk,
                              const float* __restrict__ Wv) {
  int i = blockIdx.x * blockDim.x + threadIdx.x;
  if (i >= C_ * CPAD) return;
  int o = i / CPAD, j = i - o * CPAD;
  float q = 0.f, kk = 0.f, v = 0.f;
  if (j < CP) {
    q = Wq[o * CP + j] * 0.35355339059327373f;  // fold 1/sqrt(D), D=8
    kk = Wk[o * CP + j];
    v = Wv[o * CP + j];
  }
  wpad[i] = q;
  wpad[C_ * CPAD + i] = kk;
  wpad[2 * C_ * CPAD + i] = v;
}

// LDS-pipe xor swizzle (32-lane groups). BitMode offset = (xor<<10)|0x1F.
#define SWZ(v, imm) __int_as_float(__builtin_amdgcn_ds_swizzle(__float_as_int(v), (imm)))
#define XOR4S 0x101F
#define XOR8S 0x201F

// VALU-pipe DPP ops (quad_perm within 4 lanes; row_ror within 16-lane row)
#define DPPF(v, ctrl) \
  __int_as_float(__builtin_amdgcn_mov_dpp(__float_as_int(v), (ctrl), 0xF, 0xF, 0))
#define QP_XOR1 0xB1   // quad_perm [1,0,3,2]
#define QP_XOR2 0x4E   // quad_perm [2,3,0,1]
#define ROW_ROR4 0x124 // lane i <- lane (i+4)%16  (within 16-lane row)
#define ROW_ROR8 0x128 // lane i <- lane (i+8)%16

template <int CTRL>
__device__ __forceinline__ float qbc(float v) {
  return __int_as_float(__builtin_amdgcn_mov_dpp(__float_as_int(v), CTRL, 0xF, 0xF, 0));
}

// MAC heads 2M (from a) and 2M+1 (from b), broadcast from quad-lane M.
template <int M>
__device__ __forceinline__ void mac2(float& enE, float& enO, float4 a, float4 b,
                                     float x0, float x1, float x2, float x3) {
  enE += qbc<M * 0x55>(a.x) * x0 + qbc<M * 0x55>(a.y) * x1 +
         qbc<M * 0x55>(a.z) * x2 + qbc<M * 0x55>(a.w) * x3;
  enO += qbc<M * 0x55>(b.x) * x0 + qbc<M * 0x55>(b.y) * x1 +
         qbc<M * 0x55>(b.z) * x2 + qbc<M * 0x55>(b.w) * x3;
}

// waves_per_eu(3,3): pin allocator target to 3 waves/EU -> ~170 VGPR budget.
// (launch_bounds' 2nd arg is only a MIN; the backend squeezed to 64 VGPRs and
//  spilled nb[68] -> 1.9 GB scratch traffic in round 2.)
__global__ __attribute__((amdgpu_flat_work_group_size(256, 256),
                          amdgpu_waves_per_eu(3, 3)))
void pt_attn(const float* __restrict__ pcd,
             const float* __restrict__ neighbors,
             const float* __restrict__ xyz,
             const int* __restrict__ idx_all,
             float* __restrict__ out) {
  // Single buffer: e-table [16 x 548]; x (1088 fl) and q (1040 fl) overlay its
  // start and are dead before e is written (extra barrier enforces it).
  __shared__ __align__(16) float smem[NP * ESTRIDE];  // 35072 B

  const int tid = threadIdx.x;
  const int p = tid >> 4;   // point within tile
  const int k = tid & 15;   // neighbor index
  const int blk = blockIdx.x;
  const int b = blk >> 10;
  const int n0 = (blk & 1023) << 4;
  const int n = n0 + p;

  // ---- neighbor features (B,C,N,K) -> registers; coalesced (256 contiguous
  //      floats per channel across the block) ----
  float nb[CPAD];
  {
    const float* gp = neighbors + (size_t)b * (C_ * N_ * K_) + n0 * K_ + tid;
#pragma unroll
    for (int c = 0; c < C_; ++c)
      nb[c] = gp[(size_t)c * (N_ * K_)];
  }
  {
    const int idx = idx_all[(b * N_ + n) * K_ + k];
    const float* gx = xyz + (size_t)b * (3 * N_) + idx;
    nb[64] = gx[0];
    nb[65] = gx[N_];
    nb[66] = gx[2 * N_];
    nb[67] = 0.f;  // pad (weight pad col is 0 too)
  }

  // ---- stage x = concat(pcd, xyz) for the 16 points (overlay at smem[0]) ----
  {
    const int pp = tid & 15;
    const int c0 = tid >> 4;
#pragma unroll
    for (int it = 0; it < 4; ++it) {
      int c = c0 + it * 16;
      smem[pp * CPAD + c] = pcd[((size_t)b * C_ + c) * N_ + n0 + pp];
    }
    if (tid < 48)
      smem[pp * CPAD + 64 + c0] = xyz[((size_t)b * 3 + c0) * N_ + n0 + pp];
    if (tid < 16)
      smem[pp * CPAD + 67] = 0.f;
  }
  __syncthreads();

  // ---- phase 1: q[o], o = 4k..4k+3 of point p (Wq pre-scaled) ----
  {
    const float4* xr = (const float4*)(smem + p * CPAD);  // broadcast reads
    const float4* wq = (const float4*)(wpad) + 4 * k * 17;
    float a0 = 0.f, a1 = 0.f, a2 = 0.f, a3 = 0.f;
#pragma unroll
    for (int j4 = 0; j4 < 17; ++j4) {
      float4 xv = xr[j4];
      float4 w0 = wq[j4];
      float4 w1 = wq[17 + j4];
      float4 w2 = wq[34 + j4];
      float4 w3 = wq[51 + j4];
      a0 += w0.x * xv.x + w0.y * xv.y + w0.z * xv.z + w0.w * xv.w;
      a1 += w1.x * xv.x + w1.y * xv.y + w1.z * xv.z + w1.w * xv.w;
      a2 += w2.x * xv.x + w2.y * xv.y + w2.z * xv.z + w2.w * xv.w;
      a3 += w3.x * xv.x + w3.y * xv.y + w3.z * xv.z + w3.w * xv.w;
    }
    smem[QOFF + p * QSTRIDE + 4 * k + 0] = a0;
    smem[QOFF + p * QSTRIDE + 4 * k + 1] = a1;
    smem[QOFF + p * QSTRIDE + 4 * k + 2] = a2;
    smem[QOFF + p * QSTRIDE + 4 * k + 3] = a3;
  }
  __syncthreads();

  // ---- phase 2: load q_h, then (after barrier) write e over the overlay ----
  const int h_ = k & 7;
  float qa[8];
#pragma unroll
  for (int d = 0; d < 8; ++d)
    qa[d] = smem[QOFF + p * QSTRIDE + h_ * 8 + d];
  __syncthreads();  // all q reads done before e overwrites x/q overlay

  {
    const int jh = k >> 3;
    const float4* wk = (const float4*)(wpad + C_ * CPAD) + h_ * 8 * 17;
    float4* er = (float4*)(smem + p * ESTRIDE + h_ * CPAD);
#pragma unroll
    for (int u = 0; u < 9; ++u) {
      int j4 = jh * 8 + u;  // j4=8 written by both halves with identical value
      float4 a = make_float4(0.f, 0.f, 0.f, 0.f);
#pragma unroll
      for (int d = 0; d < 8; ++d) {
        float4 w = wk[d * 17 + j4];
        a.x += qa[d] * w.x;
        a.y += qa[d] * w.y;
        a.z += qa[d] * w.z;
        a.w += qa[d] * w.w;
      }
      er[j4] = a;
    }
  }
  __syncthreads();

  // ---- phase 3: en[h] = e[h]·nb_k. Quad-lane c reads only heads {2c,2c+1}
  //      (2 b128/j4), DPP quad-broadcast shares all 8 heads (VALU pipe). ----
  float en[8];
#pragma unroll
  for (int h = 0; h < 8; ++h) en[h] = 0.f;
  {
    const float* e0 = smem + p * ESTRIDE + (2 * (k & 3)) * CPAD;
#pragma unroll
    for (int j4 = 0; j4 < 17; ++j4) {
      float4 a = *(const float4*)(e0 + 4 * j4);          // own even head
      float4 bq = *(const float4*)(e0 + CPAD + 4 * j4);  // own odd head
      float x0 = nb[4 * j4 + 0], x1 = nb[4 * j4 + 1];
      float x2 = nb[4 * j4 + 2], x3 = nb[4 * j4 + 3];
      mac2<0>(en[0], en[1], a, bq, x0, x1, x2, x3);
      mac2<1>(en[2], en[3], a, bq, x0, x1, x2, x3);
      mac2<2>(en[4], en[5], a, bq, x0, x1, x2, x3);
      mac2<3>(en[6], en[7], a, bq, x0, x1, x2, x3);
    }
  }

  // ---- softmax over the 16 k-lanes: all-reduce entirely on the VALU pipe.
  //      xor1/xor2 = quad_perm butterflies; then rotate-reduce ror4, ror8
  //      (valid for commutative max/sum; k occupies lane bits 0-3). ----
  float at[8];
#pragma unroll
  for (int h = 0; h < 8; ++h) {
    float m = en[h];
    m = fmaxf(m, DPPF(m, QP_XOR1));
    m = fmaxf(m, DPPF(m, QP_XOR2));
    m = fmaxf(m, DPPF(m, ROW_ROR4));
    m = fmaxf(m, DPPF(m, ROW_ROR8));
    float e = __expf(en[h] - m);
    float s = e;
    s += DPPF(s, QP_XOR1);
    s += DPPF(s, QP_XOR2);
    s += DPPF(s, ROW_ROR4);
    s += DPPF(s, ROW_ROR8);
    at[h] = e * __builtin_amdgcn_rcpf(s);
  }

  // ---- pre-permute: ap[i] = at[i ^ g(k)], g(k)=bitrev3(k&7); makes every
  //      reduce level use uniform register indices ----
  float ap[8];
  {
    const bool c4 = (k & 1) != 0;  // g bit2
    const bool c2 = (k & 2) != 0;  // g bit1
    const bool c1 = (k & 4) != 0;  // g bit0
    float t0[8], t1[8];
#pragma unroll
    for (int i = 0; i < 8; ++i) t0[i] = c4 ? at[i ^ 4] : at[i];
#pragma unroll
    for (int i = 0; i < 8; ++i) t1[i] = c2 ? t0[i ^ 2] : t0[i];
#pragma unroll
    for (int i = 0; i < 8; ++i) ap[i] = c1 ? t1[i ^ 1] : t1[i];
  }

  // ---- phase 4: agg_h[j] = sum_k attn[h,k]*nb_k[j]; levels xor1,xor2 on DPP
  //      (4+2 adds), xor4,xor8 on DS butterfly (1+1). Lane k ends head g(k). ----
  const int gk = ((k & 1) << 2) | (k & 2) | ((k & 4) >> 2);
  const int o_base = (gk << 3) | ((k >> 3) << 2);  // 4 output rows per lane
  float xo0 = 0.f, xo1 = 0.f, xo2 = 0.f, xo3 = 0.f;
  const float4* wv = (const float4*)(wpad + 2 * C_ * CPAD) + o_base * 17;
#pragma unroll
  for (int j4 = 0; j4 < 17; ++j4) {
    float agg0, agg1, agg2, agg3;
#pragma unroll
    for (int u = 0; u < 4; ++u) {
      float nbj = nb[4 * j4 + u];
      float s0 = ap[0] * nbj, s1 = ap[1] * nbj, s2 = ap[2] * nbj, s3 = ap[3] * nbj;
      float s4 = ap[4] * nbj, s5 = ap[5] * nbj, s6 = ap[6] * nbj, s7 = ap[7] * nbj;
      s0 += DPPF(s4, QP_XOR1);
      s1 += DPPF(s5, QP_XOR1);
      s2 += DPPF(s6, QP_XOR1);
      s3 += DPPF(s7, QP_XOR1);
      s0 += DPPF(s2, QP_XOR2);
      s1 += DPPF(s3, QP_XOR2);
      s0 += SWZ(s1, XOR4S);
      s0 += SWZ(s0, XOR8S);
      if (u == 0) agg0 = s0;
      else if (u == 1) agg1 = s0;
      else if (u == 2) agg2 = s0;
      else agg3 = s0;
    }
    float4 w0 = wv[j4];
    float4 w1 = wv[17 + j4];
    float4 w2 = wv[34 + j4];
    float4 w3 = wv[51 + j4];
    xo0 += w0.x * agg0 + w0.y * agg1 + w0.z * agg2 + w0.w * agg3;
    xo1 += w1.x * agg0 + w1.y * agg1 + w1.z * agg2 + w1.w * agg3;
    xo2 += w2.x * agg0 + w2.y * agg1 + w2.z * agg2 + w2.w * agg3;
    xo3 += w3.x * agg0 + w3.y * agg1 + w3.z * agg2 + w3.w * agg3;
  }

  // out[b][o][n], o = o_base + i
  float* op = out + ((size_t)b * C_ + o_base) * N_ + n0 + p;
  op[0] = xo0;
  op[(size_t)N_] = xo1;
  op[2 * (size_t)N_] = xo2;
  op[3 * (size_t)N_] = xo3;
}

extern "C" void kernel_launch(void* const* d_in, const int* in_sizes, int n_in,
                              void* d_out, int out_size, void* d_ws, size_t ws_size,
                              hipStream_t stream) {
  const float* pcd = (const float*)d_in[0];
  const float* neighbors = (const float*)d_in[1];
  const float* xyz = (const float*)d_in[2];
  const float* Wq = (const float*)d_in[3];
  const float* Wk = (const float*)d_in[4];
  const float* Wv = (const float*)d_in[5];
  const int* idx = (const int*)d_in[6];
  float* out = (float*)d_out;

  setup_weights<<<(C_ * CPAD + 255) / 256, 256, 0, stream>>>(Wq, Wk, Wv);
  pt_attn<<<B_ * (N_ / NP), 256, 0, stream>>>(pcd, neighbors, xyz, idx, out);
}